// Round 13
// baseline (473.167 us; speedup 1.0000x reference)
//
#include <hip/hip_runtime.h>
#include <cstdint>
#include <cstddef>

static constexpr float NEG_SLOPE_C = 0.2f;
static constexpr float EPS_C = 1e-16f;
static constexpr float LOG2E_C = 1.4426950408889634f;

#if defined(__has_builtin)
#if __has_builtin(__builtin_amdgcn_exp2f)
#define EXP2F(x) __builtin_amdgcn_exp2f(x)
#else
#define EXP2F(x) exp2f(x)
#endif
#else
#define EXP2F(x) exp2f(x)
#endif

typedef __attribute__((ext_vector_type(8))) short bf16x8;
typedef __attribute__((ext_vector_type(4))) float f32x4;

__device__ __forceinline__ short bf16_rne(float x) {
    unsigned u = __float_as_uint(x);
    u = (u + 0x7FFF + ((u >> 16) & 1)) >> 16;
    return (short)u;
}
__device__ __forceinline__ float bf16f(short s) {
    return __uint_as_float(((unsigned)(unsigned short)s) << 16);
}

// DPP-based partial-sum add: v += dpp_perm(v).
template<int CTRL>
__device__ __forceinline__ float dpp_add_f(float v) {
    int x = __builtin_amdgcn_update_dpp(0, __float_as_int(v), CTRL, 0xf, 0xf, true);
    return v + __int_as_float(x);
}

// Reduce within each aligned 4-lane quad (2 DPP steps). One quad = one head.
__device__ __forceinline__ float reduce4(float q) {
    q = dpp_add_f<0xB1>(q);      // xor1 (quad_perm [1,0,3,2])
    q = dpp_add_f<0x4E>(q);      // xor2 (quad_perm [2,3,0,1])
    return q;
}

// ---------------- CSR construction ----------------

__global__ void degree_kernel(const int* __restrict__ ei, const float* __restrict__ ew,
                              int E, int* __restrict__ cnt, float* __restrict__ wsum) {
    int e = blockIdx.x * blockDim.x + threadIdx.x;
    if (e >= E) return;
    int dst = ei[E + e];
    atomicAdd(&cnt[dst], 1);
    atomicAdd(&wsum[dst], ew[e]);
}

__global__ void scan_kernel(const int* __restrict__ cnt, const float* __restrict__ wsum,
                            int N, int E, int* __restrict__ offs, float* __restrict__ self_w) {
    __shared__ int bufA[1024];
    __shared__ int bufB[1024];
    int t = threadIdx.x;
    int chunk = (N + 1023) / 1024;
    int lo = t * chunk;
    int hi = lo + chunk; if (hi > N) hi = N; if (lo > N) lo = N;
    int s = 0;
    for (int n = lo; n < hi; ++n) s += cnt[n];
    bufA[t] = s;
    __syncthreads();
    int* srcb = bufA; int* dstb = bufB;
    for (int d = 1; d < 1024; d <<= 1) {
        int v = srcb[t];
        if (t >= d) v += srcb[t - d];
        dstb[t] = v;
        __syncthreads();
        int* tmp = srcb; srcb = dstb; dstb = tmp;
    }
    int run = (t == 0) ? 0 : srcb[t - 1];
    for (int n = lo; n < hi; ++n) { offs[n] = run; run += cnt[n]; }
    if (t == 0) offs[N] = E;
    for (int n = t; n < N; n += 1024) {
        int c = cnt[n];
        self_w[n] = (c > 0) ? (wsum[n] / (float)c) : 0.0f;
    }
}

__global__ void scatter_kernel(const int* __restrict__ ei, const float* __restrict__ ew, int E,
                               const int* __restrict__ offs, int* __restrict__ cursor,
                               int2* __restrict__ pairs) {
    int e = blockIdx.x * blockDim.x + threadIdx.x;
    if (e >= E) return;
    int dst = ei[E + e];
    int pos = offs[dst] + atomicAdd(&cursor[dst], 1);
    pairs[pos] = make_int2(ei[e], __float_as_int(ew[e]));
}

// ---------------- W prep: fp32 -> split-bf16 hi/lo in MFMA FRAGMENT ORDER -----

template<int K>
__global__ void wprep_kernel(const float* __restrict__ Wl, const float* __restrict__ Wr,
                             uint4* __restrict__ Wf) {
    const int gid = blockIdx.x * 256 + threadIdx.x;   // (K/32)*16*64 threads
    const int lane = gid & 63;
    const int t = (gid >> 6) & 15;
    const int s = gid >> 10;
    const int mr = lane & 15, q = lane >> 4;
    const int col = t * 16 + mr;
    const float* src = (col < 128) ? (Wl + col) : (Wr + col - 128);
    union { short sh[8]; uint4 u; } hv, lv;
    #pragma unroll
    for (int j = 0; j < 8; ++j) {
        const float v = src[(size_t)(s * 32 + q * 8 + j) * 128];
        const short h = bf16_rne(v);
        hv.sh[j] = h;
        lv.sh[j] = bf16_rne(v - bf16f(h));
    }
    const size_t base = (size_t)s * 2048 + (size_t)(t * 2) * 64 + lane;
    Wf[base] = hv.u;          // hi plane
    Wf[base + 64] = lv.u;     // lo plane
}

// ---------------- split-bf16 MFMA GEMM (R10-proven, unchanged) ----------------

template<int K>
__global__ __launch_bounds__(256) void gemm_mfma_kernel(
    const float* __restrict__ X, const uint4* __restrict__ Wf,
    float* __restrict__ outL, float* __restrict__ outR) {
    __shared__ uint4 wbuf[2048];          // 32 KB: one k-slice, fragment order
    const int tid = threadIdx.x;
    const int wv = tid >> 6;
    const int lane = tid & 63;
    const int q = lane >> 4;
    const int mr = lane & 15;
    const int xrow = blockIdx.x * 64 + wv * 16 + mr;

    f32x4 acc[16];
    #pragma unroll
    for (int t = 0; t < 16; ++t) acc[t] = (f32x4){0.f, 0.f, 0.f, 0.f};

    const float* xp = X + (size_t)xrow * K + q * 8;

    for (int s = 0; s < K / 32; ++s) {
        const float4 a0 = *(const float4*)(xp + s * 32);
        const float4 a1 = *(const float4*)(xp + s * 32 + 4);

        __syncthreads();                   // previous slice fully consumed
        const uint4* gsrc = Wf + (size_t)s * 2048 + wv * 512 + lane;
        #pragma unroll
        for (int i = 0; i < 8; ++i)
            wbuf[wv * 512 + i * 64 + lane] = gsrc[i * 64];
        __syncthreads();                   // slice visible

        const float av[8] = {a0.x, a0.y, a0.z, a0.w, a1.x, a1.y, a1.z, a1.w};
        bf16x8 xh, xl;
        #pragma unroll
        for (int j = 0; j < 8; ++j) {
            const short h = bf16_rne(av[j]);
            xh[j] = h;
            xl[j] = bf16_rne(av[j] - bf16f(h));
        }
        #pragma unroll
        for (int t = 0; t < 16; ++t) {
            const bf16x8 wh = *(const bf16x8*)&wbuf[(t * 2) * 64 + lane];
            const bf16x8 wl = *(const bf16x8*)&wbuf[(t * 2 + 1) * 64 + lane];
            acc[t] = __builtin_amdgcn_mfma_f32_16x16x32_bf16(wh, xh, acc[t], 0, 0, 0);
            acc[t] = __builtin_amdgcn_mfma_f32_16x16x32_bf16(wl, xh, acc[t], 0, 0, 0);
            acc[t] = __builtin_amdgcn_mfma_f32_16x16x32_bf16(wh, xl, acc[t], 0, 0, 0);
        }
    }

    const size_t ob = (size_t)xrow * 128 + q * 4;
    #pragma unroll
    for (int t = 0; t < 8; ++t) {
        *(float4*)(outL + ob + t * 16) =
            make_float4(acc[t][0], acc[t][1], acc[t][2], acc[t][3]);
        *(float4*)(outR + ob + t * 16) =
            make_float4(acc[t + 8][0], acc[t + 8][1], acc[t + 8][2], acc[t + 8][3]);
    }
}

// ---------------- fused edge softmax-aggregate: EIGHT edges per wave ----------
// Lane l: edge slot p = l>>3, within-edge lane u = l&7, channels u*16..u*16+15.
// Quad = one head (u 0-3 -> head 0, u 4-7 -> head 1), so the per-head dot is
// reduce4 = 2 DPP steps serving 8 edges at once; each lane's q IS its head's
// logit, t = exp2(q-base) is head-correct per lane. lsum is head-local
// (combined only across slots). Masked slots replace tail code (R12-proven).
// Scalar fmaf/fminf channel math (R11-proven codegen; R12's pk path reverted).
// Self-loop contributes 1/8 from each slot (exact). XCD swizzle unchanged.

__global__ __launch_bounds__(256) void edge_kernel(
    const float* __restrict__ xl, const float* __restrict__ xr,
    const int* __restrict__ offs, const int2* __restrict__ pairs,
    const float* __restrict__ self_w,
    const float* __restrict__ att, const float* __restrict__ We,
    const float* __restrict__ bias, float* __restrict__ out,
    int N, int M) {
    const int wave = __builtin_amdgcn_readfirstlane(threadIdx.x >> 6);
    const int b = blockIdx.x;
    const int hb = (b >= 10000) ? (b - 10000) : b;
    const int m = ((b >= 10000) ? 8 : 0) + (hb & 7);
    const int n = (hb >> 3) * 4 + wave;
    if (n >= N) return;
    const int lane = threadIdx.x & 63;
    const int p = lane >> 3;          // edge slot 0..7
    const int u = lane & 7;           // channel window: float4s u*4 .. u*4+3
    const int cb = u * 4;

    const float4* xlm4 = (const float4*)(xl + (size_t)m * N * 128);
    const float4* xrm4 = (const float4*)(xr + (size_t)m * N * 128);

    float4 attv[4], wev[4], xiv[4];
    #pragma unroll
    for (int i = 0; i < 4; ++i) {
        attv[i] = ((const float4*)att)[cb + i];
        attv[i].x *= LOG2E_C; attv[i].y *= LOG2E_C;
        attv[i].z *= LOG2E_C; attv[i].w *= LOG2E_C;
        wev[i] = ((const float4*)We)[cb + i];
        xiv[i] = xrm4[n * 32 + cb + i];
    }

    // per-float4 edge math: s = leaky(xi + w*we + xj), q += s·att
    #define CH4(XI, WE, AT, XJ, W, QACC)                                   \
        {                                                                  \
            float s0 = fmaf(W, WE.x, XI.x) + XJ.x;                         \
            float s1 = fmaf(W, WE.y, XI.y) + XJ.y;                         \
            float s2 = fmaf(W, WE.z, XI.z) + XJ.z;                         \
            float s3 = fmaf(W, WE.w, XI.w) + XJ.w;                         \
            s0 = fmaf(NEG_SLOPE_C - 1.0f, fminf(s0, 0.f), s0);             \
            s1 = fmaf(NEG_SLOPE_C - 1.0f, fminf(s1, 0.f), s1);             \
            s2 = fmaf(NEG_SLOPE_C - 1.0f, fminf(s2, 0.f), s2);             \
            s3 = fmaf(NEG_SLOPE_C - 1.0f, fminf(s3, 0.f), s3);             \
            QACC = fmaf(s0, AT.x, QACC);                                   \
            QACC = fmaf(s1, AT.y, QACC);                                   \
            QACC = fmaf(s2, AT.z, QACC);                                   \
            QACC = fmaf(s3, AT.w, QACC);                                   \
        }

    float base_, lsum;
    float4 acc[4];
    {   // self-loop: all 8 slots compute it; each contributes 1/8 (exact)
        const float sw = self_w[n];
        float4 xj[4];
        float q0 = 0.f, q1 = 0.f, q2 = 0.f, q3 = 0.f;
        #pragma unroll
        for (int i = 0; i < 4; ++i) xj[i] = xlm4[n * 32 + cb + i];
        CH4(xiv[0], wev[0], attv[0], xj[0], sw, q0);
        CH4(xiv[1], wev[1], attv[1], xj[1], sw, q1);
        CH4(xiv[2], wev[2], attv[2], xj[2], sw, q2);
        CH4(xiv[3], wev[3], attv[3], xj[3], sw, q3);
        base_ = reduce4((q0 + q1) + (q2 + q3));
        lsum = 0.125f;
        #pragma unroll
        for (int i = 0; i < 4; ++i)
            acc[i] = make_float4(xj[i].x * 0.125f, xj[i].y * 0.125f,
                                 xj[i].z * 0.125f, xj[i].w * 0.125f);
    }

    const int beg = offs[n], end = offs[n + 1];
    for (int e0 = beg; e0 < end; e0 += 8) {
        const int idx = e0 + p;
        const bool valid = idx < end;
        const int2 pr = pairs[valid ? idx : (end - 1)];
        const int src = pr.x;
        const float w = __int_as_float(pr.y);
        float4 xj[4];
        #pragma unroll
        for (int i = 0; i < 4; ++i) xj[i] = xlm4[src * 32 + cb + i];
        float q0 = 0.f, q1 = 0.f, q2 = 0.f, q3 = 0.f;
        CH4(xiv[0], wev[0], attv[0], xj[0], w, q0);
        CH4(xiv[1], wev[1], attv[1], xj[1], w, q1);
        CH4(xiv[2], wev[2], attv[2], xj[2], w, q2);
        CH4(xiv[3], wev[3], attv[3], xj[3], w, q3);
        const float q = reduce4((q0 + q1) + (q2 + q3));
        float t = EXP2F(q - base_);
        t = valid ? t : 0.f;
        lsum += t;
        #pragma unroll
        for (int i = 0; i < 4; ++i) {
            acc[i].x = fmaf(t, xj[i].x, acc[i].x);
            acc[i].y = fmaf(t, xj[i].y, acc[i].y);
            acc[i].z = fmaf(t, xj[i].z, acc[i].z);
            acc[i].w = fmaf(t, xj[i].w, acc[i].w);
        }
    }
    #undef CH4

    // combine the 8 edge slots (lanes u, u+8, ..., u+56 share channels; lsum
    // stays head-local because only slot bits 3..5 are crossed)
    #pragma unroll
    for (int d = 8; d <= 32; d <<= 1) {
        lsum += __shfl_xor(lsum, d, 64);
        #pragma unroll
        for (int i = 0; i < 4; ++i) {
            acc[i].x += __shfl_xor(acc[i].x, d, 64);
            acc[i].y += __shfl_xor(acc[i].y, d, 64);
            acc[i].z += __shfl_xor(acc[i].z, d, 64);
            acc[i].w += __shfl_xor(acc[i].w, d, 64);
        }
    }

    if (p == 0) {
        const float inv = 1.f / (lsum + EPS_C);
        float4* ob = (float4*)(out + (size_t)m * N * 128);
        #pragma unroll
        for (int i = 0; i < 4; ++i) {
            const float4 bi = ((const float4*)bias)[cb + i];
            float o0 = fmaf(acc[i].x, inv, bi.x);
            float o1 = fmaf(acc[i].y, inv, bi.y);
            float o2 = fmaf(acc[i].z, inv, bi.z);
            float o3 = fmaf(acc[i].w, inv, bi.w);
            o0 = o0 > 0.f ? o0 : (__expf(o0) - 1.f);
            o1 = o1 > 0.f ? o1 : (__expf(o1) - 1.f);
            o2 = o2 > 0.f ? o2 : (__expf(o2) - 1.f);
            o3 = o3 > 0.f ? o3 : (__expf(o3) - 1.f);
            ob[n * 32 + cb + i] = make_float4(o0, o1, o2, o3);
        }
    }
}

// ---------------- launch ----------------

extern "C" void kernel_launch(void* const* d_in, const int* in_sizes, int n_in,
                              void* d_out, int out_size, void* d_ws, size_t ws_size,
                              hipStream_t stream) {
    const float* x    = (const float*)d_in[0];
    const int*   ei   = (const int*)d_in[1];
    const float* ew   = (const float*)d_in[2];
    const float* Wl1  = (const float*)d_in[3];
    const float* Wr1  = (const float*)d_in[4];
    const float* att1 = (const float*)d_in[5];
    const float* We1  = (const float*)d_in[6];
    const float* b1   = (const float*)d_in[7];
    const float* Wl2  = (const float*)d_in[8];
    const float* Wr2  = (const float*)d_in[9];
    const float* att2 = (const float*)d_in[10];
    const float* We2  = (const float*)d_in[11];
    const float* b2   = (const float*)d_in[12];

    const int E = in_sizes[1] / 2;
    const int N = 5000;                 // fixed by setup_inputs
    const int R = out_size / 128;       // M*N rows
    const int M = R / N;                // B*T = 16

    char* ws = (char*)d_ws;
    size_t off = 0;
    auto alloc = [&](size_t bytes) {
        char* p = ws + off;
        off = (off + bytes + 255) & ~(size_t)255;
        return p;
    };
    int*   cnt    = (int*)  alloc((size_t)3 * N * 4);   // cnt | wsum | cursor (1 memset)
    float* wsum   = (float*)(cnt + N);
    int*   cursor = cnt + 2 * N;
    float* selfw  = (float*)alloc((size_t)N * 4);
    int*   offs   = (int*)  alloc((size_t)(N + 1) * 4);
    int2*  pairs  = (int2*) alloc((size_t)E * 8);
    uint4* wf1    = (uint4*)alloc((size_t)2 * 2048 * 16);   // K=64: 64 KB
    uint4* wf2    = (uint4*)alloc((size_t)4 * 2048 * 16);   // K=128: 128 KB
    float* bufA   = (float*)alloc((size_t)R * 128 * 4);
    float* bufB   = (float*)alloc((size_t)R * 128 * 4);
    float* bufC   = (float*)alloc((size_t)R * 128 * 4);

    hipMemsetAsync(cnt, 0, (size_t)3 * N * 4, stream);

    int eb = (E + 255) / 256;
    degree_kernel<<<eb, 256, 0, stream>>>(ei, ew, E, cnt, wsum);
    scan_kernel<<<1, 1024, 0, stream>>>(cnt, wsum, N, E, offs, selfw);
    scatter_kernel<<<eb, 256, 0, stream>>>(ei, ew, E, offs, cursor, pairs);
    wprep_kernel<64><<<8, 256, 0, stream>>>(Wl1, Wr1, wf1);
    wprep_kernel<128><<<16, 256, 0, stream>>>(Wl2, Wr2, wf2);

    const int gb = R / 64;
    const int tb = 2 * ((N + 3) / 4) * 8;   // 20000 blocks: XCD-swizzled task map

    // layer 1: K=64
    gemm_mfma_kernel<64><<<gb, 256, 0, stream>>>(x, wf1, bufA, bufB);
    edge_kernel<<<tb, 256, 0, stream>>>(bufA, bufB, offs, pairs, selfw,
                                        att1, We1, b1, bufC, N, M);
    // layer 2: K=128
    gemm_mfma_kernel<128><<<gb, 256, 0, stream>>>(bufC, wf2, bufA, bufB);
    edge_kernel<<<tb, 256, 0, stream>>>(bufA, bufB, offs, pairs, selfw,
                                        att2, We2, b2, (float*)d_out, N, M);
}

// Round 14
// 311.523 us; speedup vs baseline: 1.5189x; 1.5189x over previous
//
#include <hip/hip_runtime.h>
#include <cstdint>
#include <cstddef>

static constexpr float NEG_SLOPE_C = 0.2f;
static constexpr float EPS_C = 1e-16f;
static constexpr float LOG2E_C = 1.4426950408889634f;

#if defined(__has_builtin)
#if __has_builtin(__builtin_amdgcn_exp2f)
#define EXP2F(x) __builtin_amdgcn_exp2f(x)
#else
#define EXP2F(x) exp2f(x)
#endif
#else
#define EXP2F(x) exp2f(x)
#endif

typedef __attribute__((ext_vector_type(8))) short bf16x8;
typedef __attribute__((ext_vector_type(4))) float f32x4;

__device__ __forceinline__ short bf16_rne(float x) {
    unsigned u = __float_as_uint(x);
    u = (u + 0x7FFF + ((u >> 16) & 1)) >> 16;
    return (short)u;
}
__device__ __forceinline__ float bf16f(short s) {
    return __uint_as_float(((unsigned)(unsigned short)s) << 16);
}

// DPP-based partial-sum add: v += dpp_perm(v).
template<int CTRL>
__device__ __forceinline__ float dpp_add_f(float v) {
    int x = __builtin_amdgcn_update_dpp(0, __float_as_int(v), CTRL, 0xf, 0xf, true);
    return v + __int_as_float(x);
}

// Reduce within each 16-lane row (4 DPP steps, no DS).
__device__ __forceinline__ float reduce16(float q) {
    q = dpp_add_f<0xB1>(q);      // xor1 (quad_perm [1,0,3,2])
    q = dpp_add_f<0x4E>(q);      // xor2 (quad_perm [2,3,0,1])
    q = dpp_add_f<0x141>(q);     // xor4 (row_half_mirror)
    q = dpp_add_f<0x140>(q);     // xor8 (row_mirror)
    return q;
}

// ---------------- CSR construction ----------------

__global__ void degree_kernel(const int* __restrict__ ei, const float* __restrict__ ew,
                              int E, int* __restrict__ cnt, float* __restrict__ wsum) {
    int e = blockIdx.x * blockDim.x + threadIdx.x;
    if (e >= E) return;
    int dst = ei[E + e];
    atomicAdd(&cnt[dst], 1);
    atomicAdd(&wsum[dst], ew[e]);
}

__global__ void scan_kernel(const int* __restrict__ cnt, const float* __restrict__ wsum,
                            int N, int E, int* __restrict__ offs, float* __restrict__ self_w) {
    __shared__ int bufA[1024];
    __shared__ int bufB[1024];
    int t = threadIdx.x;
    int chunk = (N + 1023) / 1024;
    int lo = t * chunk;
    int hi = lo + chunk; if (hi > N) hi = N; if (lo > N) lo = N;
    int s = 0;
    for (int n = lo; n < hi; ++n) s += cnt[n];
    bufA[t] = s;
    __syncthreads();
    int* srcb = bufA; int* dstb = bufB;
    for (int d = 1; d < 1024; d <<= 1) {
        int v = srcb[t];
        if (t >= d) v += srcb[t - d];
        dstb[t] = v;
        __syncthreads();
        int* tmp = srcb; srcb = dstb; dstb = tmp;
    }
    int run = (t == 0) ? 0 : srcb[t - 1];
    for (int n = lo; n < hi; ++n) { offs[n] = run; run += cnt[n]; }
    if (t == 0) offs[N] = E;
    for (int n = t; n < N; n += 1024) {
        int c = cnt[n];
        self_w[n] = (c > 0) ? (wsum[n] / (float)c) : 0.0f;
    }
}

__global__ void scatter_kernel(const int* __restrict__ ei, const float* __restrict__ ew, int E,
                               const int* __restrict__ offs, int* __restrict__ cursor,
                               int2* __restrict__ pairs) {
    int e = blockIdx.x * blockDim.x + threadIdx.x;
    if (e >= E) return;
    int dst = ei[E + e];
    int pos = offs[dst] + atomicAdd(&cursor[dst], 1);
    pairs[pos] = make_int2(ei[e], __float_as_int(ew[e]));
}

// ---------------- W prep: fp32 -> split-bf16 hi/lo in MFMA FRAGMENT ORDER -----

template<int K>
__global__ void wprep_kernel(const float* __restrict__ Wl, const float* __restrict__ Wr,
                             uint4* __restrict__ Wf) {
    const int gid = blockIdx.x * 256 + threadIdx.x;   // (K/32)*16*64 threads
    const int lane = gid & 63;
    const int t = (gid >> 6) & 15;
    const int s = gid >> 10;
    const int mr = lane & 15, q = lane >> 4;
    const int col = t * 16 + mr;
    const float* src = (col < 128) ? (Wl + col) : (Wr + col - 128);
    union { short sh[8]; uint4 u; } hv, lv;
    #pragma unroll
    for (int j = 0; j < 8; ++j) {
        const float v = src[(size_t)(s * 32 + q * 8 + j) * 128];
        const short h = bf16_rne(v);
        hv.sh[j] = h;
        lv.sh[j] = bf16_rne(v - bf16f(h));
    }
    const size_t base = (size_t)s * 2048 + (size_t)(t * 2) * 64 + lane;
    Wf[base] = hv.u;          // hi plane
    Wf[base + 64] = lv.u;     // lo plane
}

// ---------------- split-bf16 MFMA GEMM: [outL|outR] = X[R x K] @ [Wl|Wr] --------
// R14 change: 512-thread blocks (128 rows, 8 waves). The 32 KB W k-slice in
// LDS now serves 8 waves instead of 4 -> W L2 traffic and barrier count per
// output row halve. Wave-level occupancy is unchanged (~100 VGPR -> 16
// waves/CU either way). Everything else R10-proven: fragment-ordered Wf,
// conflict-free ds_read_b128 frags, 3-MFMA split-bf16 triple, coalesced
// float4 epilogue. FULL unroll wherever acc[] is indexed (R8 spill lesson).

template<int K>
__global__ __launch_bounds__(512) void gemm_mfma_kernel(
    const float* __restrict__ X, const uint4* __restrict__ Wf,
    float* __restrict__ outL, float* __restrict__ outR) {
    __shared__ uint4 wbuf[2048];          // 32 KB: one k-slice, fragment order
    const int tid = threadIdx.x;
    const int wv = tid >> 6;              // 0..7
    const int lane = tid & 63;
    const int q = lane >> 4;
    const int mr = lane & 15;
    const int xrow = blockIdx.x * 128 + wv * 16 + mr;

    f32x4 acc[16];
    #pragma unroll
    for (int t = 0; t < 16; ++t) acc[t] = (f32x4){0.f, 0.f, 0.f, 0.f};

    const float* xp = X + (size_t)xrow * K + q * 8;

    for (int s = 0; s < K / 32; ++s) {
        const float4 a0 = *(const float4*)(xp + s * 32);
        const float4 a1 = *(const float4*)(xp + s * 32 + 4);

        __syncthreads();                   // previous slice fully consumed
        // 2048 uint4 / 512 threads = 4 per thread, coalesced
        const uint4* gsrc = Wf + (size_t)s * 2048 + wv * 256 + lane;
        #pragma unroll
        for (int i = 0; i < 4; ++i)
            wbuf[wv * 256 + i * 64 + lane] = gsrc[i * 64];
        __syncthreads();                   // slice visible

        const float av[8] = {a0.x, a0.y, a0.z, a0.w, a1.x, a1.y, a1.z, a1.w};
        bf16x8 xh, xl;
        #pragma unroll
        for (int j = 0; j < 8; ++j) {
            const short h = bf16_rne(av[j]);
            xh[j] = h;
            xl[j] = bf16_rne(av[j] - bf16f(h));
        }
        #pragma unroll
        for (int t = 0; t < 16; ++t) {
            const bf16x8 wh = *(const bf16x8*)&wbuf[(t * 2) * 64 + lane];
            const bf16x8 wl = *(const bf16x8*)&wbuf[(t * 2 + 1) * 64 + lane];
            acc[t] = __builtin_amdgcn_mfma_f32_16x16x32_bf16(wh, xh, acc[t], 0, 0, 0);
            acc[t] = __builtin_amdgcn_mfma_f32_16x16x32_bf16(wl, xh, acc[t], 0, 0, 0);
            acc[t] = __builtin_amdgcn_mfma_f32_16x16x32_bf16(wh, xl, acc[t], 0, 0, 0);
        }
    }

    const size_t ob = (size_t)xrow * 128 + q * 4;
    #pragma unroll
    for (int t = 0; t < 8; ++t) {
        *(float4*)(outL + ob + t * 16) =
            make_float4(acc[t][0], acc[t][1], acc[t][2], acc[t][3]);
        *(float4*)(outR + ob + t * 16) =
            make_float4(acc[t + 8][0], acc[t + 8][1], acc[t + 8][2], acc[t + 8][3]);
    }
}

// ---------------- fused edge softmax-aggregate: TWO edges per wave ------------
// R11-proven kernel, byte-for-byte (65.4 us, VALUBusy 82%). R12 (4-slot pk)
// and R13 (8-slot) both regressed: the slot-combine epilogue scales as
// (ch/lane+1)*log2(slots) per node and occupancy drops with VGPR — 2 slots
// is the measured optimum of this family. Do not widen again.

__global__ __launch_bounds__(256) void edge_kernel(
    const float* __restrict__ xl, const float* __restrict__ xr,
    const int* __restrict__ offs, const int2* __restrict__ pairs,
    const float* __restrict__ self_w,
    const float* __restrict__ att, const float* __restrict__ We,
    const float* __restrict__ bias, float* __restrict__ out,
    int N, int M) {
    const int wave = __builtin_amdgcn_readfirstlane(threadIdx.x >> 6);
    const int b = blockIdx.x;
    const int hb = (b >= 10000) ? (b - 10000) : b;
    const int m = ((b >= 10000) ? 8 : 0) + (hb & 7);
    const int n = (hb >> 3) * 4 + wave;
    if (n >= N) return;
    const int lane = threadIdx.x & 63;
    const int j = lane & 31;
    const bool hi = lane >= 32;

    const float4* xlm4 = (const float4*)(xl + (size_t)m * N * 128);
    const float4* xrm4 = (const float4*)(xr + (size_t)m * N * 128);

    float4 att4 = ((const float4*)att)[j];
    att4.x *= LOG2E_C; att4.y *= LOG2E_C; att4.z *= LOG2E_C; att4.w *= LOG2E_C;
    const float4 we4 = ((const float4*)We)[j];
    const float4 xi4 = xrm4[n * 32 + j];

    float base, lsum;
    float4 acc;
    {   // self-loop: both halves compute it; each contributes 0.5x (exact)
        const float sw = self_w[n];
        const float4 xj = xlm4[n * 32 + j];
        float s0 = fmaf(sw, we4.x, xi4.x) + xj.x;
        float s1 = fmaf(sw, we4.y, xi4.y) + xj.y;
        float s2 = fmaf(sw, we4.z, xi4.z) + xj.z;
        float s3 = fmaf(sw, we4.w, xi4.w) + xj.w;
        s0 = fmaf(NEG_SLOPE_C - 1.0f, fminf(s0, 0.f), s0);
        s1 = fmaf(NEG_SLOPE_C - 1.0f, fminf(s1, 0.f), s1);
        s2 = fmaf(NEG_SLOPE_C - 1.0f, fminf(s2, 0.f), s2);
        s3 = fmaf(NEG_SLOPE_C - 1.0f, fminf(s3, 0.f), s3);
        float q = s0 * att4.x;
        q = fmaf(s1, att4.y, q);
        q = fmaf(s2, att4.z, q);
        q = fmaf(s3, att4.w, q);
        base = reduce16(q);               // per-row = per-head self logit
        lsum = 0.5f;
        acc = make_float4(xj.x * 0.5f, xj.y * 0.5f, xj.z * 0.5f, xj.w * 0.5f);
    }

    const int beg = offs[n], end = offs[n + 1];
    int e = beg;
    #pragma unroll 2
    for (; e + 2 <= end; e += 2) {
        const int2 prA = pairs[e];
        const int2 prB = pairs[e + 1];
        const int src = hi ? prB.x : prA.x;
        const float w = __int_as_float(hi ? prB.y : prA.y);
        const float4 xj = xlm4[src * 32 + j];
        float s0 = fmaf(w, we4.x, xi4.x) + xj.x;
        float s1 = fmaf(w, we4.y, xi4.y) + xj.y;
        float s2 = fmaf(w, we4.z, xi4.z) + xj.z;
        float s3 = fmaf(w, we4.w, xi4.w) + xj.w;
        s0 = fmaf(NEG_SLOPE_C - 1.0f, fminf(s0, 0.f), s0);
        s1 = fmaf(NEG_SLOPE_C - 1.0f, fminf(s1, 0.f), s1);
        s2 = fmaf(NEG_SLOPE_C - 1.0f, fminf(s2, 0.f), s2);
        s3 = fmaf(NEG_SLOPE_C - 1.0f, fminf(s3, 0.f), s3);
        float q = s0 * att4.x;
        q = fmaf(s1, att4.y, q);
        q = fmaf(s2, att4.z, q);
        q = fmaf(s3, att4.w, q);
        q = reduce16(q);
        const float t = EXP2F(q - base);
        lsum += t;
        acc.x = fmaf(t, xj.x, acc.x);
        acc.y = fmaf(t, xj.y, acc.y);
        acc.z = fmaf(t, xj.z, acc.z);
        acc.w = fmaf(t, xj.w, acc.w);
    }
    if (e < end) {   // odd tail: both halves same edge; half 1 zeroed
        const int2 pr = pairs[e];
        const int src = pr.x;
        const float w = __int_as_float(pr.y);
        const float4 xj = xlm4[src * 32 + j];
        float s0 = fmaf(w, we4.x, xi4.x) + xj.x;
        float s1 = fmaf(w, we4.y, xi4.y) + xj.y;
        float s2 = fmaf(w, we4.z, xi4.z) + xj.z;
        float s3 = fmaf(w, we4.w, xi4.w) + xj.w;
        s0 = fmaf(NEG_SLOPE_C - 1.0f, fminf(s0, 0.f), s0);
        s1 = fmaf(NEG_SLOPE_C - 1.0f, fminf(s1, 0.f), s1);
        s2 = fmaf(NEG_SLOPE_C - 1.0f, fminf(s2, 0.f), s2);
        s3 = fmaf(NEG_SLOPE_C - 1.0f, fminf(s3, 0.f), s3);
        float q = s0 * att4.x;
        q = fmaf(s1, att4.y, q);
        q = fmaf(s2, att4.z, q);
        q = fmaf(s3, att4.w, q);
        q = reduce16(q);
        float t = EXP2F(q - base);
        t = hi ? 0.f : t;
        lsum += t;
        acc.x = fmaf(t, xj.x, acc.x);
        acc.y = fmaf(t, xj.y, acc.y);
        acc.z = fmaf(t, xj.z, acc.z);
        acc.w = fmaf(t, xj.w, acc.w);
    }

    // cross-half combine (once per node)
    lsum += __shfl_xor(lsum, 32, 64);
    acc.x += __shfl_xor(acc.x, 32, 64);
    acc.y += __shfl_xor(acc.y, 32, 64);
    acc.z += __shfl_xor(acc.z, 32, 64);
    acc.w += __shfl_xor(acc.w, 32, 64);

    const float inv = 1.f / (lsum + EPS_C);
    const float4 b4 = ((const float4*)bias)[j];
    float o0 = fmaf(acc.x, inv, b4.x);
    float o1 = fmaf(acc.y, inv, b4.y);
    float o2 = fmaf(acc.z, inv, b4.z);
    float o3 = fmaf(acc.w, inv, b4.w);
    o0 = o0 > 0.f ? o0 : (__expf(o0) - 1.f);
    o1 = o1 > 0.f ? o1 : (__expf(o1) - 1.f);
    o2 = o2 > 0.f ? o2 : (__expf(o2) - 1.f);
    o3 = o3 > 0.f ? o3 : (__expf(o3) - 1.f);
    if (!hi) {
        ((float4*)(out + (size_t)m * N * 128))[n * 32 + j] =
            make_float4(o0, o1, o2, o3);
    }
}

// ---------------- launch ----------------

extern "C" void kernel_launch(void* const* d_in, const int* in_sizes, int n_in,
                              void* d_out, int out_size, void* d_ws, size_t ws_size,
                              hipStream_t stream) {
    const float* x    = (const float*)d_in[0];
    const int*   ei   = (const int*)d_in[1];
    const float* ew   = (const float*)d_in[2];
    const float* Wl1  = (const float*)d_in[3];
    const float* Wr1  = (const float*)d_in[4];
    const float* att1 = (const float*)d_in[5];
    const float* We1  = (const float*)d_in[6];
    const float* b1   = (const float*)d_in[7];
    const float* Wl2  = (const float*)d_in[8];
    const float* Wr2  = (const float*)d_in[9];
    const float* att2 = (const float*)d_in[10];
    const float* We2  = (const float*)d_in[11];
    const float* b2   = (const float*)d_in[12];

    const int E = in_sizes[1] / 2;
    const int N = 5000;                 // fixed by setup_inputs
    const int R = out_size / 128;       // M*N rows
    const int M = R / N;                // B*T = 16

    char* ws = (char*)d_ws;
    size_t off = 0;
    auto alloc = [&](size_t bytes) {
        char* p = ws + off;
        off = (off + bytes + 255) & ~(size_t)255;
        return p;
    };
    int*   cnt    = (int*)  alloc((size_t)3 * N * 4);   // cnt | wsum | cursor (1 memset)
    float* wsum   = (float*)(cnt + N);
    int*   cursor = cnt + 2 * N;
    float* selfw  = (float*)alloc((size_t)N * 4);
    int*   offs   = (int*)  alloc((size_t)(N + 1) * 4);
    int2*  pairs  = (int2*) alloc((size_t)E * 8);
    uint4* wf1    = (uint4*)alloc((size_t)2 * 2048 * 16);   // K=64: 64 KB
    uint4* wf2    = (uint4*)alloc((size_t)4 * 2048 * 16);   // K=128: 128 KB
    float* bufA   = (float*)alloc((size_t)R * 128 * 4);
    float* bufB   = (float*)alloc((size_t)R * 128 * 4);
    float* bufC   = (float*)alloc((size_t)R * 128 * 4);

    hipMemsetAsync(cnt, 0, (size_t)3 * N * 4, stream);

    int eb = (E + 255) / 256;
    degree_kernel<<<eb, 256, 0, stream>>>(ei, ew, E, cnt, wsum);
    scan_kernel<<<1, 1024, 0, stream>>>(cnt, wsum, N, E, offs, selfw);
    scatter_kernel<<<eb, 256, 0, stream>>>(ei, ew, E, offs, cursor, pairs);
    wprep_kernel<64><<<8, 256, 0, stream>>>(Wl1, Wr1, wf1);
    wprep_kernel<128><<<16, 256, 0, stream>>>(Wl2, Wr2, wf2);

    const int gb = R / 128;                 // 512-thread gemm blocks: 128 rows
    const int tb = 2 * ((N + 3) / 4) * 8;   // 20000 blocks: XCD-swizzled task map

    // layer 1: K=64
    gemm_mfma_kernel<64><<<gb, 512, 0, stream>>>(x, wf1, bufA, bufB);
    edge_kernel<<<tb, 256, 0, stream>>>(bufA, bufB, offs, pairs, selfw,
                                        att1, We1, b1, bufC, N, M);
    // layer 2: K=128
    gemm_mfma_kernel<128><<<gb, 512, 0, stream>>>(bufC, wf2, bufA, bufB);
    edge_kernel<<<tb, 256, 0, stream>>>(bufA, bufB, offs, pairs, selfw,
                                        att2, We2, b2, (float*)d_out, N, M);
}